// Round 2
// baseline (514.718 us; speedup 1.0000x reference)
//
#include <hip/hip_runtime.h>

typedef __attribute__((ext_vector_type(8))) short short8;
typedef __attribute__((ext_vector_type(4))) float f32x4;
typedef unsigned short u16;
typedef unsigned int u32;

#define NH 16

#if __has_builtin(__builtin_amdgcn_exp2f)
#define EXP2(x) __builtin_amdgcn_exp2f(x)
#else
#define EXP2(x) exp2f(x)
#endif

__device__ __forceinline__ u32 f2bf(float f) {
  u32 u = __builtin_bit_cast(u32, f);
  return (u + 0x7fffu + ((u >> 16) & 1u)) >> 16;  // round-nearest-even bf16 bits
}

// ---------- convert x + Wq,Wk,Wv,Wo (fp32) -> bf16 into ws ----------
__global__ __launch_bounds__(256) void k_convert(
    const float* __restrict__ x, const float* __restrict__ wq,
    const float* __restrict__ wk, const float* __restrict__ wv,
    const float* __restrict__ wo, u16* __restrict__ dst) {
  int i = blockIdx.x * 256 + threadIdx.x;
  size_t e = (size_t)i * 4;
  const float* s; size_t off;
  if (e < 8388608ull)       { s = x;  off = e; }
  else if (e < 9437184ull)  { s = wq; off = e - 8388608ull; }
  else if (e < 10485760ull) { s = wk; off = e - 9437184ull; }
  else if (e < 11534336ull) { s = wv; off = e - 10485760ull; }
  else                      { s = wo; off = e - 11534336ull; }
  float4 d = *(const float4*)(s + off);
  ushort4 o;
  o.x = (u16)f2bf(d.x); o.y = (u16)f2bf(d.y);
  o.z = (u16)f2bf(d.z); o.w = (u16)f2bf(d.w);
  *(ushort4*)(dst + e) = o;
}

// ---------- shared GEMM core: C[128x128] = A[128xK] * B[128xK]^T ----------
// Reg-staged (round-0 proven): compiler hoists next-tile global loads into
// VGPRs across the barrier during MFMA -> free 1-deep pipeline at K=1024.
// (gload_lds variant without counted-vmcnt 8-phase measured SLOWER here, R1.)
#define GEMM_CORE(Aptr, Bptr)                                                   \
  __shared__ u16 As[128 * 72];                                                  \
  __shared__ u16 Bs[128 * 72];                                                  \
  const int tid = threadIdx.x;                                                  \
  const int wave = tid >> 6, lane = tid & 63;                                   \
  const int wr = wave >> 1, wc = wave & 1;                                      \
  const int quad = lane >> 4, l16 = lane & 15;                                  \
  const int m0 = blockIdx.y * 128, n0 = blockIdx.x * 128;                       \
  f32x4 acc[4][4];                                                              \
  {                                                                             \
    f32x4 z = {0.f, 0.f, 0.f, 0.f};                                             \
    for (int a = 0; a < 4; ++a) for (int b2 = 0; b2 < 4; ++b2) acc[a][b2] = z;  \
  }                                                                             \
  for (int k0 = 0; k0 < 1024; k0 += 64) {                                       \
    _Pragma("unroll")                                                           \
    for (int i = 0; i < 4; ++i) {                                               \
      int c = i * 256 + tid;                                                    \
      int row = c >> 3, cc = c & 7;                                             \
      *(uint4*)(&As[row * 72 + cc * 8]) =                                       \
          *(const uint4*)(Aptr + (size_t)(m0 + row) * 1024 + k0 + cc * 8);      \
      *(uint4*)(&Bs[row * 72 + cc * 8]) =                                       \
          *(const uint4*)(Bptr + (size_t)(n0 + row) * 1024 + k0 + cc * 8);      \
    }                                                                           \
    __syncthreads();                                                            \
    _Pragma("unroll")                                                           \
    for (int ks = 0; ks < 2; ++ks) {                                            \
      short8 af[4], bfr[4];                                                     \
      _Pragma("unroll")                                                         \
      for (int t = 0; t < 4; ++t)                                               \
        af[t] = *(const short8*)(&As[(wr * 64 + t * 16 + l16) * 72 + ks * 32 + quad * 8]); \
      _Pragma("unroll")                                                         \
      for (int t = 0; t < 4; ++t)                                               \
        bfr[t] = *(const short8*)(&Bs[(wc * 64 + t * 16 + l16) * 72 + ks * 32 + quad * 8]); \
      _Pragma("unroll")                                                         \
      for (int mt = 0; mt < 4; ++mt) {                                          \
        _Pragma("unroll")                                                       \
        for (int nt = 0; nt < 4; ++nt)                                          \
          acc[mt][nt] = __builtin_amdgcn_mfma_f32_16x16x32_bf16(                \
              af[mt], bfr[nt], acc[mt][nt], 0, 0, 0);                           \
      }                                                                         \
    }                                                                           \
    __syncthreads();                                                            \
  }

// ---------- QKV projection: out scattered to [B,H,T,Dh] bf16 ----------
__global__ __launch_bounds__(256, 2) void k_gemm_qkv(
    const u16* __restrict__ A, const u16* __restrict__ W,
    const float* __restrict__ bq, const float* __restrict__ bk,
    const float* __restrict__ bv, u16* __restrict__ qkv) {
  const int z = blockIdx.z;
  const u16* Bw = W + (size_t)z * 1048576;
  const float* bias = (z == 0) ? bq : (z == 1) ? bk : bv;
  u16* out = qkv + (size_t)z * 8388608;
  GEMM_CORE(A, Bw)
  // q: fold 1/sqrt(64) AND log2(e) (attention softmax runs in exp2 domain)
  const float scl = (z == 0) ? 0.125f * 1.44269504088896340736f : 1.0f;
  #pragma unroll
  for (int mt = 0; mt < 4; ++mt) {
    #pragma unroll
    for (int nt = 0; nt < 4; ++nt) {
      int n = n0 + wc * 64 + nt * 16 + l16;
      float bn = bias[n];
      int h = n >> 6, d = n & 63;
      #pragma unroll
      for (int r = 0; r < 4; ++r) {
        int m = m0 + wr * 64 + mt * 16 + quad * 4 + r;
        int b = m >> 11, t = m & 2047;
        float val = (acc[mt][nt][r] + bn) * scl;
        out[(((size_t)(b * NH + h) * 2048 + t) << 6) + d] = (u16)f2bf(val);
      }
    }
  }
}

// ---------- output projection: fp32 out [8192][1024] ----------
__global__ __launch_bounds__(256, 2) void k_gemm_out(
    const u16* __restrict__ A, const u16* __restrict__ Bw,
    const float* __restrict__ bias, float* __restrict__ out) {
  GEMM_CORE(A, Bw)
  #pragma unroll
  for (int mt = 0; mt < 4; ++mt) {
    #pragma unroll
    for (int nt = 0; nt < 4; ++nt) {
      int n = n0 + wc * 64 + nt * 16 + l16;
      float bn = bias[n];
      #pragma unroll
      for (int r = 0; r < 4; ++r) {
        int m = m0 + wr * 64 + mt * 16 + quad * 4 + r;
        out[(size_t)m * 1024 + n] = acc[mt][nt][r] + bn;
      }
    }
  }
}

// ---------- V transpose: [B,H,T,Dh] -> [B,H,Dh,T] bf16 ----------
__global__ __launch_bounds__(256) void k_vtrans(const u16* __restrict__ v,
                                                u16* __restrict__ vt) {
  int t0 = blockIdx.x * 64;
  int bh = blockIdx.y;
  const u16* vs = v + (size_t)bh * 2048 * 64;
  u16* vd = vt + (size_t)bh * 64 * 2048;
  int tid = threadIdx.x;
  #pragma unroll
  for (int it = 0; it < 2; ++it) {
    int c = it * 256 + tid;
    int d = c >> 3, tc = c & 7;
    u16 tmp[8];
    #pragma unroll
    for (int j = 0; j < 8; ++j)
      tmp[j] = vs[(size_t)(t0 + tc * 8 + j) * 64 + d];
    uint4 pk;
    pk.x = (u32)tmp[0] | ((u32)tmp[1] << 16);
    pk.y = (u32)tmp[2] | ((u32)tmp[3] << 16);
    pk.z = (u32)tmp[4] | ((u32)tmp[5] << 16);
    pk.w = (u32)tmp[6] | ((u32)tmp[7] << 16);
    *(uint4*)(vd + (size_t)d * 2048 + t0 + tc * 8) = pk;
  }
}

// ---------- flash attention, S^T orientation, paired q-tiles --------------
// Block bx handles q-tiles qtB=bx (short) and qtA=31-bx (long): constant 33
// tiles of work per block -> 1024 uniform blocks, shared K/V staging for the
// common kt prefix. S^T = K*Q^T puts q on lanes: softmax is in-register
// (depth-4 trees) + 2 shfl_xor; P packs to LDS via u32 bit-ops.
// R2: for kt <= qtB the A- and B-tile steps are FUSED into one basic block:
// two independent softmax chains interleave in the scheduler (2x ILP on the
// exposed-latency chain), and K-frag / V-frag LDS reads are shared (halved).

// single-tile step (tail region, A only)
#define ATTN_STEP(QF0, QF1, O, MI, LI, PW, DIAG)                               \
  {                                                                            \
    f32x4 st[4];                                                               \
    _Pragma("unroll")                                                          \
    for (int nt = 0; nt < 4; ++nt) {                                           \
      short8 kf0 = *(const short8*)(&Ks[(nt * 16 + l16) * 72 + quad * 8]);     \
      short8 kf1 = *(const short8*)(&Ks[(nt * 16 + l16) * 72 + 32 + quad * 8]);\
      f32x4 z4 = {0.f, 0.f, 0.f, 0.f};                                         \
      z4 = __builtin_amdgcn_mfma_f32_16x16x32_bf16(kf0, QF0, z4, 0, 0, 0);     \
      st[nt] = __builtin_amdgcn_mfma_f32_16x16x32_bf16(kf1, QF1, z4, 0, 0, 0); \
    }                                                                          \
    if (DIAG) {                                                                \
      int q_loc = wave * 16 + l16;                                             \
      _Pragma("unroll")                                                        \
      for (int nt = 0; nt < 4; ++nt) {                                         \
        _Pragma("unroll")                                                      \
        for (int r = 0; r < 4; ++r) {                                          \
          int k_loc = nt * 16 + quad * 4 + r;                                  \
          if (k_loc > q_loc) st[nt][r] = -1e30f;                               \
        }                                                                      \
      }                                                                        \
    }                                                                          \
    float mq[4];                                                               \
    _Pragma("unroll")                                                          \
    for (int nt = 0; nt < 4; ++nt)                                             \
      mq[nt] = fmaxf(fmaxf(st[nt][0], st[nt][1]), fmaxf(st[nt][2], st[nt][3]));\
    float mx = fmaxf(fmaxf(mq[0], mq[1]), fmaxf(mq[2], mq[3]));                \
    mx = fmaxf(mx, __shfl_xor(mx, 16, 64));                                    \
    mx = fmaxf(mx, __shfl_xor(mx, 32, 64));                                    \
    float mnew = fmaxf(MI, mx);                                                \
    float alpha = EXP2(MI - mnew);                                             \
    MI = mnew;                                                                 \
    LI *= alpha;                                                               \
    _Pragma("unroll")                                                          \
    for (int r = 0; r < 4; ++r) {                                              \
      float av = __shfl(alpha, quad * 4 + r, 16);                              \
      _Pragma("unroll")                                                        \
      for (int dt = 0; dt < 4; ++dt) O[dt][r] *= av;                           \
    }                                                                          \
    float sq[4];                                                               \
    _Pragma("unroll")                                                          \
    for (int nt = 0; nt < 4; ++nt) {                                           \
      float p0 = EXP2(st[nt][0] - mnew);                                       \
      float p1 = EXP2(st[nt][1] - mnew);                                       \
      float p2 = EXP2(st[nt][2] - mnew);                                       \
      float p3 = EXP2(st[nt][3] - mnew);                                       \
      sq[nt] = (p0 + p1) + (p2 + p3);                                          \
      uint2 pk;                                                                \
      pk.x = f2bf(p0) | (f2bf(p1) << 16);                                      \
      pk.y = f2bf(p2) | (f2bf(p3) << 16);                                      \
      *(uint2*)(&PW[l16 * 72 + nt * 16 + quad * 4]) = pk;                      \
    }                                                                          \
    float sum = (sq[0] + sq[1]) + (sq[2] + sq[3]);                             \
    sum += __shfl_xor(sum, 16, 64);                                            \
    sum += __shfl_xor(sum, 32, 64);                                            \
    LI += sum;                                                                 \
    _Pragma("unroll")                                                          \
    for (int ks = 0; ks < 2; ++ks) {                                           \
      short8 pf = *(const short8*)(PW + l16 * 72 + ks * 32 + quad * 8);        \
      _Pragma("unroll")                                                        \
      for (int dt = 0; dt < 4; ++dt) {                                         \
        short8 vf = *(const short8*)(&Vs[(dt * 16 + l16) * 72 + ks * 32 + quad * 8]); \
        O[dt] = __builtin_amdgcn_mfma_f32_16x16x32_bf16(pf, vf, O[dt], 0, 0, 0); \
      }                                                                        \
    }                                                                          \
  }

// fused step: both q-tiles, shared K/V fragments, interleaved chains.
// DIAGB: apply causal mask to the B tile (kt == qtB). A never needs the
// mask here (qtA >= 16 > qtB, handled in the tail region).
#define ATTN_STEP2(DIAGB)                                                      \
  {                                                                            \
    f32x4 stA[4], stB[4];                                                      \
    _Pragma("unroll")                                                          \
    for (int nt = 0; nt < 4; ++nt) {                                           \
      short8 kf0 = *(const short8*)(&Ks[(nt * 16 + l16) * 72 + quad * 8]);     \
      short8 kf1 = *(const short8*)(&Ks[(nt * 16 + l16) * 72 + 32 + quad * 8]);\
      f32x4 z4 = {0.f, 0.f, 0.f, 0.f};                                         \
      f32x4 a0 = __builtin_amdgcn_mfma_f32_16x16x32_bf16(kf0, qA0, z4, 0, 0, 0); \
      f32x4 b0 = __builtin_amdgcn_mfma_f32_16x16x32_bf16(kf0, qB0, z4, 0, 0, 0); \
      stA[nt] = __builtin_amdgcn_mfma_f32_16x16x32_bf16(kf1, qA1, a0, 0, 0, 0);  \
      stB[nt] = __builtin_amdgcn_mfma_f32_16x16x32_bf16(kf1, qB1, b0, 0, 0, 0);  \
    }                                                                          \
    if (DIAGB) {                                                               \
      int q_loc = wave * 16 + l16;                                             \
      _Pragma("unroll")                                                        \
      for (int nt = 0; nt < 4; ++nt) {                                         \
        _Pragma("unroll")                                                      \
        for (int r = 0; r < 4; ++r) {                                          \
          int k_loc = nt * 16 + quad * 4 + r;                                  \
          if (k_loc > q_loc) stB[nt][r] = -1e30f;                              \
        }                                                                      \
      }                                                                        \
    }                                                                          \
    float mqA[4], mqB[4];                                                      \
    _Pragma("unroll")                                                          \
    for (int nt = 0; nt < 4; ++nt) {                                           \
      mqA[nt] = fmaxf(fmaxf(stA[nt][0], stA[nt][1]), fmaxf(stA[nt][2], stA[nt][3])); \
      mqB[nt] = fmaxf(fmaxf(stB[nt][0], stB[nt][1]), fmaxf(stB[nt][2], stB[nt][3])); \
    }                                                                          \
    float mxA = fmaxf(fmaxf(mqA[0], mqA[1]), fmaxf(mqA[2], mqA[3]));           \
    float mxB = fmaxf(fmaxf(mqB[0], mqB[1]), fmaxf(mqB[2], mqB[3]));           \
    mxA = fmaxf(mxA, __shfl_xor(mxA, 16, 64));                                 \
    mxB = fmaxf(mxB, __shfl_xor(mxB, 16, 64));                                 \
    mxA = fmaxf(mxA, __shfl_xor(mxA, 32, 64));                                 \
    mxB = fmaxf(mxB, __shfl_xor(mxB, 32, 64));                                 \
    float mnewA = fmaxf(mA, mxA), mnewB = fmaxf(mB, mxB);                      \
    float alphaA = EXP2(mA - mnewA), alphaB = EXP2(mB - mnewB);                \
    mA = mnewA; mB = mnewB;                                                    \
    lA *= alphaA; lB *= alphaB;                                                \
    _Pragma("unroll")                                                          \
    for (int r = 0; r < 4; ++r) {                                              \
      float avA = __shfl(alphaA, quad * 4 + r, 16);                            \
      float avB = __shfl(alphaB, quad * 4 + r, 16);                            \
      _Pragma("unroll")                                                        \
      for (int dt = 0; dt < 4; ++dt) { oA[dt][r] *= avA; oB[dt][r] *= avB; }   \
    }                                                                          \
    float sqA[4], sqB[4];                                                      \
    _Pragma("unroll")                                                          \
    for (int nt = 0; nt < 4; ++nt) {                                           \
      float a0 = EXP2(stA[nt][0] - mnewA);                                     \
      float a1 = EXP2(stA[nt][1] - mnewA);                                     \
      float a2 = EXP2(stA[nt][2] - mnewA);                                     \
      float a3 = EXP2(stA[nt][3] - mnewA);                                     \
      float b0 = EXP2(stB[nt][0] - mnewB);                                     \
      float b1 = EXP2(stB[nt][1] - mnewB);                                     \
      float b2 = EXP2(stB[nt][2] - mnewB);                                     \
      float b3 = EXP2(stB[nt][3] - mnewB);                                     \
      sqA[nt] = (a0 + a1) + (a2 + a3);                                         \
      sqB[nt] = (b0 + b1) + (b2 + b3);                                         \
      uint2 pkA, pkB;                                                          \
      pkA.x = f2bf(a0) | (f2bf(a1) << 16);                                     \
      pkA.y = f2bf(a2) | (f2bf(a3) << 16);                                     \
      pkB.x = f2bf(b0) | (f2bf(b1) << 16);                                     \
      pkB.y = f2bf(b2) | (f2bf(b3) << 16);                                     \
      *(uint2*)(&pwA[l16 * 72 + nt * 16 + quad * 4]) = pkA;                    \
      *(uint2*)(&pwB[l16 * 72 + nt * 16 + quad * 4]) = pkB;                    \
    }                                                                          \
    float sumA = (sqA[0] + sqA[1]) + (sqA[2] + sqA[3]);                        \
    float sumB = (sqB[0] + sqB[1]) + (sqB[2] + sqB[3]);                        \
    sumA += __shfl_xor(sumA, 16, 64);                                          \
    sumB += __shfl_xor(sumB, 16, 64);                                          \
    sumA += __shfl_xor(sumA, 32, 64);                                          \
    sumB += __shfl_xor(sumB, 32, 64);                                          \
    lA += sumA; lB += sumB;                                                    \
    _Pragma("unroll")                                                          \
    for (int ks = 0; ks < 2; ++ks) {                                           \
      short8 pfA = *(const short8*)(pwA + l16 * 72 + ks * 32 + quad * 8);      \
      short8 pfB = *(const short8*)(pwB + l16 * 72 + ks * 32 + quad * 8);      \
      _Pragma("unroll")                                                        \
      for (int dt = 0; dt < 4; ++dt) {                                         \
        short8 vf = *(const short8*)(&Vs[(dt * 16 + l16) * 72 + ks * 32 + quad * 8]); \
        oA[dt] = __builtin_amdgcn_mfma_f32_16x16x32_bf16(pfA, vf, oA[dt], 0, 0, 0); \
        oB[dt] = __builtin_amdgcn_mfma_f32_16x16x32_bf16(pfB, vf, oB[dt], 0, 0, 0); \
      }                                                                        \
    }                                                                          \
  }

#define ATTN_EPI(O, LI, QT)                                                    \
  _Pragma("unroll")                                                            \
  for (int r = 0; r < 4; ++r) {                                                \
    float lv = __shfl(LI, quad * 4 + r, 16);                                   \
    float inv = 1.0f / lv;                                                     \
    int t = (QT) * 64 + wave * 16 + quad * 4 + r;                              \
    _Pragma("unroll")                                                          \
    for (int dt = 0; dt < 4; ++dt) {                                           \
      int d = dt * 16 + l16;                                                   \
      y[(((size_t)b * 2048 + t) * NH + h) * 64 + d] = (u16)f2bf(O[dt][r] * inv); \
    }                                                                          \
  }

__global__ __launch_bounds__(256, 4) void k_attn(
    const u16* __restrict__ q, const u16* __restrict__ k,
    const u16* __restrict__ vt, u16* __restrict__ y) {
  const int tid = threadIdx.x;
  const int wave = tid >> 6, lane = tid & 63;
  const int quad = lane >> 4, l16 = lane & 15;
  const int bx = blockIdx.x, bh = blockIdx.y;
  const int qtB = bx, qtA = 31 - bx;   // qtB in 0..15, qtA in 16..31
  const int b = bh >> 4, h = bh & 15;

  __shared__ u16 Ks[64 * 72];
  __shared__ u16 Vs[64 * 72];           // [d][kidx]
  __shared__ u16 PsA[4 * 16 * 72];
  __shared__ u16 PsB[4 * 16 * 72];

  const u16* qbA = q + ((size_t)bh * 2048 + qtA * 64 + wave * 16 + l16) * 64;
  short8 qA0 = *(const short8*)(qbA + quad * 8);
  short8 qA1 = *(const short8*)(qbA + 32 + quad * 8);
  const u16* qbB = q + ((size_t)bh * 2048 + qtB * 64 + wave * 16 + l16) * 64;
  short8 qB0 = *(const short8*)(qbB + quad * 8);
  short8 qB1 = *(const short8*)(qbB + 32 + quad * 8);

  f32x4 oA[4], oB[4];
  {
    f32x4 z = {0.f, 0.f, 0.f, 0.f};
    #pragma unroll
    for (int dt = 0; dt < 4; ++dt) { oA[dt] = z; oB[dt] = z; }
  }
  float mA = -1e30f, lA = 0.f, mB = -1e30f, lB = 0.f;

  u16* pwA = PsA + wave * 16 * 72;
  u16* pwB = PsB + wave * 16 * 72;

  const u16* kbase = k + (size_t)bh * 2048 * 64;
  const u16* vbase = vt + (size_t)bh * 64 * 2048;
  const int r0 = tid >> 3, cc = tid & 7;

  uint4 kr[2], vr[2];
  #pragma unroll
  for (int i = 0; i < 2; ++i) {
    int row = i * 32 + r0;
    kr[i] = *(const uint4*)(kbase + (size_t)row * 64 + cc * 8);
    vr[i] = *(const uint4*)(vbase + (size_t)row * 2048 + cc * 8);
  }

  for (int kt = 0; kt <= qtA; ++kt) {
    #pragma unroll
    for (int i = 0; i < 2; ++i) {
      int row = i * 32 + r0;
      *(uint4*)(&Ks[row * 72 + cc * 8]) = kr[i];
      *(uint4*)(&Vs[row * 72 + cc * 8]) = vr[i];
    }
    __syncthreads();

    if (kt < qtA) {  // register-prefetch next K/V tile across the compute
      const u16* kb = kbase + (size_t)(kt + 1) * 64 * 64;
      const u16* vb = vbase + (kt + 1) * 64;
      #pragma unroll
      for (int i = 0; i < 2; ++i) {
        int row = i * 32 + r0;
        kr[i] = *(const uint4*)(kb + (size_t)row * 64 + cc * 8);
        vr[i] = *(const uint4*)(vb + (size_t)row * 2048 + cc * 8);
      }
    }

    if (kt <= qtB) {
      ATTN_STEP2((kt == qtB))
    } else {
      ATTN_STEP(qA0, qA1, oA, mA, lA, pwA, (kt == qtA))
    }
    __syncthreads();
  }

  ATTN_EPI(oA, lA, qtA)
  ATTN_EPI(oB, lB, qtB)
}

extern "C" void kernel_launch(void* const* d_in, const int* in_sizes, int n_in,
                              void* d_out, int out_size, void* d_ws, size_t ws_size,
                              hipStream_t stream) {
  const float* x  = (const float*)d_in[0];
  const float* Wq = (const float*)d_in[1];
  const float* bq = (const float*)d_in[2];
  const float* Wk = (const float*)d_in[3];
  const float* bk = (const float*)d_in[4];
  const float* Wv = (const float*)d_in[5];
  const float* bv = (const float*)d_in[6];
  const float* Wo = (const float*)d_in[7];
  const float* bo = (const float*)d_in[8];
  float* out = (float*)d_out;

  u16* ws  = (u16*)d_ws;
  u16* xb  = ws;                   // 8388608   x bf16 [8192][1024]
  u16* Wb  = ws + 8388608;         // 4x1048576 Wq|Wk|Wv|Wo bf16
  u16* qkv = ws + 12582912;        // 3x8388608 q|k|v [B,H,T,Dh] bf16
  u16* vt  = ws + 37748736;        // 8388608   v^T [B,H,Dh,T] bf16
  u16* y   = ws + 46137344;        // 8388608   attn out [B,T,H,Dh] bf16

  k_convert<<<dim3(12288), dim3(256), 0, stream>>>(x, Wq, Wk, Wv, Wo, ws);
  k_gemm_qkv<<<dim3(8, 64, 3), dim3(256), 0, stream>>>(xb, Wb, bq, bk, bv, qkv);
  k_vtrans<<<dim3(32, 64), dim3(256), 0, stream>>>(qkv + 2 * 8388608, vt);
  k_attn<<<dim3(16, 64), dim3(256), 0, stream>>>(qkv, qkv + 8388608, vt, y);
  k_gemm_out<<<dim3(8, 64), dim3(256), 0, stream>>>(y, Wb + 3 * 1048576, bo, out);
}

// Round 3
// 496.078 us; speedup vs baseline: 1.0376x; 1.0376x over previous
//
#include <hip/hip_runtime.h>

typedef __attribute__((ext_vector_type(8))) short short8;
typedef __attribute__((ext_vector_type(4))) float f32x4;
typedef unsigned short u16;
typedef unsigned int u32;

#define NH 16

#if __has_builtin(__builtin_amdgcn_exp2f)
#define EXP2(x) __builtin_amdgcn_exp2f(x)
#else
#define EXP2(x) exp2f(x)
#endif

__device__ __forceinline__ u32 f2bf(float f) {
  u32 u = __builtin_bit_cast(u32, f);
  return (u + 0x7fffu + ((u >> 16) & 1u)) >> 16;  // round-nearest-even bf16 bits
}

// ---------- convert x + Wq,Wk,Wv,Wo (fp32) -> bf16 into ws ----------
__global__ __launch_bounds__(256) void k_convert(
    const float* __restrict__ x, const float* __restrict__ wq,
    const float* __restrict__ wk, const float* __restrict__ wv,
    const float* __restrict__ wo, u16* __restrict__ dst) {
  int i = blockIdx.x * 256 + threadIdx.x;
  size_t e = (size_t)i * 4;
  const float* s; size_t off;
  if (e < 8388608ull)       { s = x;  off = e; }
  else if (e < 9437184ull)  { s = wq; off = e - 8388608ull; }
  else if (e < 10485760ull) { s = wk; off = e - 9437184ull; }
  else if (e < 11534336ull) { s = wv; off = e - 10485760ull; }
  else                      { s = wo; off = e - 11534336ull; }
  float4 d = *(const float4*)(s + off);
  ushort4 o;
  o.x = (u16)f2bf(d.x); o.y = (u16)f2bf(d.y);
  o.z = (u16)f2bf(d.z); o.w = (u16)f2bf(d.w);
  *(ushort4*)(dst + e) = o;
}

// ---------- shared GEMM core: C[128x128] = A[128xK] * B[128xK]^T ----------
// Reg-staged (round-0 proven): compiler hoists next-tile global loads into
// VGPRs across the barrier during MFMA -> free 1-deep pipeline at K=1024.
// (gload_lds without counted-vmcnt 8-phase measured SLOWER here, R1.)
#define GEMM_CORE(Aptr, Bptr)                                                   \
  __shared__ u16 As[128 * 72];                                                  \
  __shared__ u16 Bs[128 * 72];                                                  \
  const int tid = threadIdx.x;                                                  \
  const int wave = tid >> 6, lane = tid & 63;                                   \
  const int wr = wave >> 1, wc = wave & 1;                                      \
  const int quad = lane >> 4, l16 = lane & 15;                                  \
  const int m0 = blockIdx.y * 128, n0 = blockIdx.x * 128;                       \
  f32x4 acc[4][4];                                                              \
  {                                                                             \
    f32x4 z = {0.f, 0.f, 0.f, 0.f};                                             \
    for (int a = 0; a < 4; ++a) for (int b2 = 0; b2 < 4; ++b2) acc[a][b2] = z;  \
  }                                                                             \
  for (int k0 = 0; k0 < 1024; k0 += 64) {                                       \
    _Pragma("unroll")                                                           \
    for (int i = 0; i < 4; ++i) {                                               \
      int c = i * 256 + tid;                                                    \
      int row = c >> 3, cc = c & 7;                                             \
      *(uint4*)(&As[row * 72 + cc * 8]) =                                       \
          *(const uint4*)(Aptr + (size_t)(m0 + row) * 1024 + k0 + cc * 8);      \
      *(uint4*)(&Bs[row * 72 + cc * 8]) =                                       \
          *(const uint4*)(Bptr + (size_t)(n0 + row) * 1024 + k0 + cc * 8);      \
    }                                                                           \
    __syncthreads();                                                            \
    _Pragma("unroll")                                                           \
    for (int ks = 0; ks < 2; ++ks) {                                            \
      short8 af[4], bfr[4];                                                     \
      _Pragma("unroll")                                                         \
      for (int t = 0; t < 4; ++t)                                               \
        af[t] = *(const short8*)(&As[(wr * 64 + t * 16 + l16) * 72 + ks * 32 + quad * 8]); \
      _Pragma("unroll")                                                         \
      for (int t = 0; t < 4; ++t)                                               \
        bfr[t] = *(const short8*)(&Bs[(wc * 64 + t * 16 + l16) * 72 + ks * 32 + quad * 8]); \
      _Pragma("unroll")                                                         \
      for (int mt = 0; mt < 4; ++mt) {                                          \
        _Pragma("unroll")                                                       \
        for (int nt = 0; nt < 4; ++nt)                                          \
          acc[mt][nt] = __builtin_amdgcn_mfma_f32_16x16x32_bf16(                \
              af[mt], bfr[nt], acc[mt][nt], 0, 0, 0);                           \
      }                                                                         \
    }                                                                           \
    __syncthreads();                                                            \
  }

// ---------- QKV projection: out scattered to [B,H,T,Dh] bf16 ----------
__global__ __launch_bounds__(256, 2) void k_gemm_qkv(
    const u16* __restrict__ A, const u16* __restrict__ W,
    const float* __restrict__ bq, const float* __restrict__ bk,
    const float* __restrict__ bv, u16* __restrict__ qkv) {
  const int z = blockIdx.z;
  const u16* Bw = W + (size_t)z * 1048576;
  const float* bias = (z == 0) ? bq : (z == 1) ? bk : bv;
  u16* out = qkv + (size_t)z * 8388608;
  GEMM_CORE(A, Bw)
  // q: fold 1/sqrt(64) AND log2(e) (attention softmax runs in exp2 domain)
  const float scl = (z == 0) ? 0.125f * 1.44269504088896340736f : 1.0f;
  #pragma unroll
  for (int mt = 0; mt < 4; ++mt) {
    #pragma unroll
    for (int nt = 0; nt < 4; ++nt) {
      int n = n0 + wc * 64 + nt * 16 + l16;
      float bn = bias[n];
      int h = n >> 6, d = n & 63;
      #pragma unroll
      for (int r = 0; r < 4; ++r) {
        int m = m0 + wr * 64 + mt * 16 + quad * 4 + r;
        int b = m >> 11, t = m & 2047;
        float val = (acc[mt][nt][r] + bn) * scl;
        out[(((size_t)(b * NH + h) * 2048 + t) << 6) + d] = (u16)f2bf(val);
      }
    }
  }
}

// ---------- output projection: fp32 out [8192][1024] ----------
__global__ __launch_bounds__(256, 2) void k_gemm_out(
    const u16* __restrict__ A, const u16* __restrict__ Bw,
    const float* __restrict__ bias, float* __restrict__ out) {
  GEMM_CORE(A, Bw)
  #pragma unroll
  for (int mt = 0; mt < 4; ++mt) {
    #pragma unroll
    for (int nt = 0; nt < 4; ++nt) {
      int n = n0 + wc * 64 + nt * 16 + l16;
      float bn = bias[n];
      #pragma unroll
      for (int r = 0; r < 4; ++r) {
        int m = m0 + wr * 64 + mt * 16 + quad * 4 + r;
        out[(size_t)m * 1024 + n] = acc[mt][nt][r] + bn;
      }
    }
  }
}

// ---------- V transpose: [B,H,T,Dh] -> [B,H,Dh,T] bf16 ----------
__global__ __launch_bounds__(256) void k_vtrans(const u16* __restrict__ v,
                                                u16* __restrict__ vt) {
  int t0 = blockIdx.x * 64;
  int bh = blockIdx.y;
  const u16* vs = v + (size_t)bh * 2048 * 64;
  u16* vd = vt + (size_t)bh * 64 * 2048;
  int tid = threadIdx.x;
  #pragma unroll
  for (int it = 0; it < 2; ++it) {
    int c = it * 256 + tid;
    int d = c >> 3, tc = c & 7;
    u16 tmp[8];
    #pragma unroll
    for (int j = 0; j < 8; ++j)
      tmp[j] = vs[(size_t)(t0 + tc * 8 + j) * 64 + d];
    uint4 pk;
    pk.x = (u32)tmp[0] | ((u32)tmp[1] << 16);
    pk.y = (u32)tmp[2] | ((u32)tmp[3] << 16);
    pk.z = (u32)tmp[4] | ((u32)tmp[5] << 16);
    pk.w = (u32)tmp[6] | ((u32)tmp[7] << 16);
    *(uint4*)(vd + (size_t)d * 2048 + t0 + tc * 8) = pk;
  }
}

// ---------- flash attention, S^T orientation, ONE q-tile per block --------
// R3: single q-tile per block (2048 blocks), P redistribution fully
// in-register via 16 shfl + 8 cndmask (the quad-exchange is closed over the
// 4 quads at fixed l16), PsA/PsB LDS eliminated -> 18432 B/block ->
// 8 blocks/CU. __launch_bounds__(256,8) targets VGPR<=64 for 32 waves/CU,
// attacking the R0 latency-bound profile (Mfma 8.5 + VALU 23 ~= occ 30).
// Longest-tile-first within each bh + bijective XCD chunking (32 same-bh
// blocks -> one XCD; 512KB K/V per bh fits the 4MB XCD L2).
__global__ __launch_bounds__(256, 8) void k_attn(
    const u16* __restrict__ q, const u16* __restrict__ k,
    const u16* __restrict__ vt, u16* __restrict__ y) {
  const int tid = threadIdx.x;
  const int wave = tid >> 6, lane = tid & 63;
  const int quad = lane >> 4, l16 = lane & 15;
  const int wg = blockIdx.x;                 // 0..2047
  const int xw = (wg & 7) * 256 + (wg >> 3); // bijective XCD chunking
  const int bh = xw >> 5;
  const int qt = 31 - (xw & 31);             // longest-first within bh
  const int b = bh >> 4, h = bh & 15;

  __shared__ u16 Ks[64 * 72];
  __shared__ u16 Vs[64 * 72];                // [d][kidx]

  const u16* qb = q + ((size_t)bh * 2048 + qt * 64 + wave * 16 + l16) * 64;
  short8 q0 = *(const short8*)(qb + quad * 8);
  short8 q1 = *(const short8*)(qb + 32 + quad * 8);

  f32x4 o[4];
  {
    f32x4 z = {0.f, 0.f, 0.f, 0.f};
    #pragma unroll
    for (int dt = 0; dt < 4; ++dt) o[dt] = z;
  }
  float mi = -1e30f, li = 0.f;

  const u16* kbase = k + (size_t)bh * 131072;
  const u16* vbase = vt + (size_t)bh * 131072;
  const int r0 = tid >> 3, cc = tid & 7;
  // shfl source lanes for the P quad-exchange (see derivation in notes):
  // target (quad,ks) pulls W[2ks+hi] words from s0 (j=0..3) and s1 (j=4..7)
  const int s0 = ((quad & 1) << 5) + l16, s1 = s0 + 16;
  const int hi = quad >> 1;

  for (int kt = 0; kt <= qt; ++kt) {
    const u16* kb = kbase + (size_t)kt * 4096;
    const u16* vb = vbase + kt * 64;
    uint4 kr0 = *(const uint4*)(kb + (size_t)r0 * 64 + cc * 8);
    uint4 kr1 = *(const uint4*)(kb + (size_t)(r0 + 32) * 64 + cc * 8);
    uint4 vr0 = *(const uint4*)(vb + (size_t)r0 * 2048 + cc * 8);
    uint4 vr1 = *(const uint4*)(vb + (size_t)(r0 + 32) * 2048 + cc * 8);
    __syncthreads();  // previous step's LDS reads complete
    *(uint4*)(&Ks[r0 * 72 + cc * 8]) = kr0;
    *(uint4*)(&Ks[(r0 + 32) * 72 + cc * 8]) = kr1;
    *(uint4*)(&Vs[r0 * 72 + cc * 8]) = vr0;
    *(uint4*)(&Vs[(r0 + 32) * 72 + cc * 8]) = vr1;
    __syncthreads();

    // --- QK^T: st[nt][r] = S[k = nt*16+quad*4+r][q = l16] (exp2 domain) ---
    f32x4 st[4];
    #pragma unroll
    for (int nt = 0; nt < 4; ++nt) {
      short8 kf0 = *(const short8*)(&Ks[(nt * 16 + l16) * 72 + quad * 8]);
      short8 kf1 = *(const short8*)(&Ks[(nt * 16 + l16) * 72 + 32 + quad * 8]);
      f32x4 z4 = {0.f, 0.f, 0.f, 0.f};
      z4 = __builtin_amdgcn_mfma_f32_16x16x32_bf16(kf0, q0, z4, 0, 0, 0);
      st[nt] = __builtin_amdgcn_mfma_f32_16x16x32_bf16(kf1, q1, z4, 0, 0, 0);
    }
    if (kt == qt) {  // causal diagonal tile
      int q_loc = wave * 16 + l16;
      #pragma unroll
      for (int nt = 0; nt < 4; ++nt) {
        #pragma unroll
        for (int r = 0; r < 4; ++r) {
          int k_loc = nt * 16 + quad * 4 + r;
          if (k_loc > q_loc) st[nt][r] = -1e30f;
        }
      }
    }

    // --- online softmax (tree-reduce in register, 2 shfl_xor per stat) ---
    float mq[4];
    #pragma unroll
    for (int nt = 0; nt < 4; ++nt)
      mq[nt] = fmaxf(fmaxf(st[nt][0], st[nt][1]), fmaxf(st[nt][2], st[nt][3]));
    float mx = fmaxf(fmaxf(mq[0], mq[1]), fmaxf(mq[2], mq[3]));
    mx = fmaxf(mx, __shfl_xor(mx, 16, 64));
    mx = fmaxf(mx, __shfl_xor(mx, 32, 64));
    float mnew = fmaxf(mi, mx);
    float alpha = EXP2(mi - mnew);
    mi = mnew;
    li *= alpha;
    #pragma unroll
    for (int r = 0; r < 4; ++r) {
      float av = __shfl(alpha, quad * 4 + r, 16);
      #pragma unroll
      for (int dt = 0; dt < 4; ++dt) o[dt][r] *= av;
    }

    u32 Wx[4], Wy[4];
    float sq[4];
    #pragma unroll
    for (int nt = 0; nt < 4; ++nt) {
      float p0 = EXP2(st[nt][0] - mnew);
      float p1 = EXP2(st[nt][1] - mnew);
      float p2 = EXP2(st[nt][2] - mnew);
      float p3 = EXP2(st[nt][3] - mnew);
      sq[nt] = (p0 + p1) + (p2 + p3);
      Wx[nt] = f2bf(p0) | (f2bf(p1) << 16);
      Wy[nt] = f2bf(p2) | (f2bf(p3) << 16);
    }
    float sum = (sq[0] + sq[1]) + (sq[2] + sq[3]);
    sum += __shfl_xor(sum, 16, 64);
    sum += __shfl_xor(sum, 32, 64);
    li += sum;

    // --- in-register P redistribution to PV A-fragment layout ---
    // receiver (quad,ks) needs P[q=l16][k=ks*32+quad*8+j]; candidates are
    // W[2ks+0]/W[2ks+1] at lanes s0/s1, selected by receiver's hi.
    uint4 t0, t1;
    {
      u32 e, f;
      e = __shfl(Wx[0], s0, 64); f = __shfl(Wx[1], s0, 64); t0.x = hi ? f : e;
      e = __shfl(Wy[0], s0, 64); f = __shfl(Wy[1], s0, 64); t0.y = hi ? f : e;
      e = __shfl(Wx[0], s1, 64); f = __shfl(Wx[1], s1, 64); t0.z = hi ? f : e;
      e = __shfl(Wy[0], s1, 64); f = __shfl(Wy[1], s1, 64); t0.w = hi ? f : e;
      e = __shfl(Wx[2], s0, 64); f = __shfl(Wx[3], s0, 64); t1.x = hi ? f : e;
      e = __shfl(Wy[2], s0, 64); f = __shfl(Wy[3], s0, 64); t1.y = hi ? f : e;
      e = __shfl(Wx[2], s1, 64); f = __shfl(Wx[3], s1, 64); t1.z = hi ? f : e;
      e = __shfl(Wy[2], s1, 64); f = __shfl(Wy[3], s1, 64); t1.w = hi ? f : e;
    }
    short8 pf0 = __builtin_bit_cast(short8, t0);
    short8 pf1 = __builtin_bit_cast(short8, t1);

    // --- PV ---
    #pragma unroll
    for (int dt = 0; dt < 4; ++dt) {
      short8 vf0 = *(const short8*)(&Vs[(dt * 16 + l16) * 72 + quad * 8]);
      short8 vf1 = *(const short8*)(&Vs[(dt * 16 + l16) * 72 + 32 + quad * 8]);
      o[dt] = __builtin_amdgcn_mfma_f32_16x16x32_bf16(pf0, vf0, o[dt], 0, 0, 0);
      o[dt] = __builtin_amdgcn_mfma_f32_16x16x32_bf16(pf1, vf1, o[dt], 0, 0, 0);
    }
  }

  // --- epilogue ---
  #pragma unroll
  for (int r = 0; r < 4; ++r) {
    float lv = __shfl(li, quad * 4 + r, 16);
    float inv = 1.0f / lv;
    int t = qt * 64 + wave * 16 + quad * 4 + r;
    #pragma unroll
    for (int dt = 0; dt < 4; ++dt) {
      int d = dt * 16 + l16;
      y[(((size_t)b * 2048 + t) * NH + h) * 64 + d] = (u16)f2bf(o[dt][r] * inv);
    }
  }
}

extern "C" void kernel_launch(void* const* d_in, const int* in_sizes, int n_in,
                              void* d_out, int out_size, void* d_ws, size_t ws_size,
                              hipStream_t stream) {
  const float* x  = (const float*)d_in[0];
  const float* Wq = (const float*)d_in[1];
  const float* bq = (const float*)d_in[2];
  const float* Wk = (const float*)d_in[3];
  const float* bk = (const float*)d_in[4];
  const float* Wv = (const float*)d_in[5];
  const float* bv = (const float*)d_in[6];
  const float* Wo = (const float*)d_in[7];
  const float* bo = (const float*)d_in[8];
  float* out = (float*)d_out;

  u16* ws  = (u16*)d_ws;
  u16* xb  = ws;                   // 8388608   x bf16 [8192][1024]
  u16* Wb  = ws + 8388608;         // 4x1048576 Wq|Wk|Wv|Wo bf16
  u16* qkv = ws + 12582912;        // 3x8388608 q|k|v [B,H,T,Dh] bf16
  u16* vt  = ws + 37748736;        // 8388608   v^T [B,H,Dh,T] bf16
  u16* y   = ws + 46137344;        // 8388608   attn out [B,T,H,Dh] bf16

  k_convert<<<dim3(12288), dim3(256), 0, stream>>>(x, Wq, Wk, Wv, Wo, ws);
  k_gemm_qkv<<<dim3(8, 64, 3), dim3(256), 0, stream>>>(xb, Wb, bq, bk, bv, qkv);
  k_vtrans<<<dim3(32, 64), dim3(256), 0, stream>>>(qkv + 2 * 8388608, vt);
  k_attn<<<dim3(2048), dim3(256), 0, stream>>>(qkv, qkv + 8388608, vt, y);
  k_gemm_out<<<dim3(8, 64), dim3(256), 0, stream>>>(y, Wb + 3 * 1048576, bo, out);
}

// Round 4
// 309.141 us; speedup vs baseline: 1.6650x; 1.6047x over previous
//
#include <hip/hip_runtime.h>

typedef __attribute__((ext_vector_type(8))) short short8;
typedef __attribute__((ext_vector_type(4))) float f32x4;
typedef unsigned short u16;
typedef unsigned int u32;

#define NH 16

#if __has_builtin(__builtin_amdgcn_exp2f)
#define EXP2(x) __builtin_amdgcn_exp2f(x)
#else
#define EXP2(x) exp2f(x)
#endif

__device__ __forceinline__ u32 f2bf(float f) {
  u32 u = __builtin_bit_cast(u32, f);
  return (u + 0x7fffu + ((u >> 16) & 1u)) >> 16;  // round-nearest-even bf16 bits
}

// ---------- convert x + Wq,Wk,Wv,Wo (fp32) -> bf16 into ws ----------
__global__ __launch_bounds__(256) void k_convert(
    const float* __restrict__ x, const float* __restrict__ wq,
    const float* __restrict__ wk, const float* __restrict__ wv,
    const float* __restrict__ wo, u16* __restrict__ dst) {
  int i = blockIdx.x * 256 + threadIdx.x;
  size_t e = (size_t)i * 4;
  const float* s; size_t off;
  if (e < 8388608ull)       { s = x;  off = e; }
  else if (e < 9437184ull)  { s = wq; off = e - 8388608ull; }
  else if (e < 10485760ull) { s = wk; off = e - 9437184ull; }
  else if (e < 11534336ull) { s = wv; off = e - 10485760ull; }
  else                      { s = wo; off = e - 11534336ull; }
  float4 d = *(const float4*)(s + off);
  ushort4 o;
  o.x = (u16)f2bf(d.x); o.y = (u16)f2bf(d.y);
  o.z = (u16)f2bf(d.z); o.w = (u16)f2bf(d.w);
  *(ushort4*)(dst + e) = o;
}

// ---------- shared GEMM core: C[128x128] = A[128xK] * B[128xK]^T ----------
// Reg-staged (round-0 proven): compiler hoists next-tile global loads into
// VGPRs across the barrier during MFMA -> free 1-deep pipeline at K=1024.
// (gload_lds without counted-vmcnt 8-phase measured SLOWER here, R1.)
#define GEMM_CORE(Aptr, Bptr)                                                   \
  __shared__ u16 As[128 * 72];                                                  \
  __shared__ u16 Bs[128 * 72];                                                  \
  const int tid = threadIdx.x;                                                  \
  const int wave = tid >> 6, lane = tid & 63;                                   \
  const int wr = wave >> 1, wc = wave & 1;                                      \
  const int quad = lane >> 4, l16 = lane & 15;                                  \
  const int m0 = blockIdx.y * 128, n0 = blockIdx.x * 128;                       \
  f32x4 acc[4][4];                                                              \
  {                                                                             \
    f32x4 z = {0.f, 0.f, 0.f, 0.f};                                             \
    for (int a = 0; a < 4; ++a) for (int b2 = 0; b2 < 4; ++b2) acc[a][b2] = z;  \
  }                                                                             \
  for (int k0 = 0; k0 < 1024; k0 += 64) {                                       \
    _Pragma("unroll")                                                           \
    for (int i = 0; i < 4; ++i) {                                               \
      int c = i * 256 + tid;                                                    \
      int row = c >> 3, cc = c & 7;                                             \
      *(uint4*)(&As[row * 72 + cc * 8]) =                                       \
          *(const uint4*)(Aptr + (size_t)(m0 + row) * 1024 + k0 + cc * 8);      \
      *(uint4*)(&Bs[row * 72 + cc * 8]) =                                       \
          *(const uint4*)(Bptr + (size_t)(n0 + row) * 1024 + k0 + cc * 8);      \
    }                                                                           \
    __syncthreads();                                                            \
    _Pragma("unroll")                                                           \
    for (int ks = 0; ks < 2; ++ks) {                                            \
      short8 af[4], bfr[4];                                                     \
      _Pragma("unroll")                                                         \
      for (int t = 0; t < 4; ++t)                                               \
        af[t] = *(const short8*)(&As[(wr * 64 + t * 16 + l16) * 72 + ks * 32 + quad * 8]); \
      _Pragma("unroll")                                                         \
      for (int t = 0; t < 4; ++t)                                               \
        bfr[t] = *(const short8*)(&Bs[(wc * 64 + t * 16 + l16) * 72 + ks * 32 + quad * 8]); \
      _Pragma("unroll")                                                         \
      for (int mt = 0; mt < 4; ++mt) {                                          \
        _Pragma("unroll")                                                       \
        for (int nt = 0; nt < 4; ++nt)                                          \
          acc[mt][nt] = __builtin_amdgcn_mfma_f32_16x16x32_bf16(                \
              af[mt], bfr[nt], acc[mt][nt], 0, 0, 0);                           \
      }                                                                         \
    }                                                                           \
    __syncthreads();                                                            \
  }

// ---------- QKV projection: out scattered to [B,H,T,Dh] bf16 ----------
__global__ __launch_bounds__(256, 2) void k_gemm_qkv(
    const u16* __restrict__ A, const u16* __restrict__ W,
    const float* __restrict__ bq, const float* __restrict__ bk,
    const float* __restrict__ bv, u16* __restrict__ qkv) {
  const int z = blockIdx.z;
  const u16* Bw = W + (size_t)z * 1048576;
  const float* bias = (z == 0) ? bq : (z == 1) ? bk : bv;
  u16* out = qkv + (size_t)z * 8388608;
  GEMM_CORE(A, Bw)
  // q: fold 1/sqrt(64) AND log2(e) (attention softmax runs in exp2 domain)
  const float scl = (z == 0) ? 0.125f * 1.44269504088896340736f : 1.0f;
  #pragma unroll
  for (int mt = 0; mt < 4; ++mt) {
    #pragma unroll
    for (int nt = 0; nt < 4; ++nt) {
      int n = n0 + wc * 64 + nt * 16 + l16;
      float bn = bias[n];
      int h = n >> 6, d = n & 63;
      #pragma unroll
      for (int r = 0; r < 4; ++r) {
        int m = m0 + wr * 64 + mt * 16 + quad * 4 + r;
        int b = m >> 11, t = m & 2047;
        float val = (acc[mt][nt][r] + bn) * scl;
        out[(((size_t)(b * NH + h) * 2048 + t) << 6) + d] = (u16)f2bf(val);
      }
    }
  }
}

// ---------- output projection: fp32 out [8192][1024] ----------
__global__ __launch_bounds__(256, 2) void k_gemm_out(
    const u16* __restrict__ A, const u16* __restrict__ Bw,
    const float* __restrict__ bias, float* __restrict__ out) {
  GEMM_CORE(A, Bw)
  #pragma unroll
  for (int mt = 0; mt < 4; ++mt) {
    #pragma unroll
    for (int nt = 0; nt < 4; ++nt) {
      int n = n0 + wc * 64 + nt * 16 + l16;
      float bn = bias[n];
      #pragma unroll
      for (int r = 0; r < 4; ++r) {
        int m = m0 + wr * 64 + mt * 16 + quad * 4 + r;
        out[(size_t)m * 1024 + n] = acc[mt][nt][r] + bn;
      }
    }
  }
}

// ---------- V transpose: [B,H,T,Dh] -> [B,H,Dh,T] bf16 ----------
__global__ __launch_bounds__(256) void k_vtrans(const u16* __restrict__ v,
                                                u16* __restrict__ vt) {
  int t0 = blockIdx.x * 64;
  int bh = blockIdx.y;
  const u16* vs = v + (size_t)bh * 2048 * 64;
  u16* vd = vt + (size_t)bh * 64 * 2048;
  int tid = threadIdx.x;
  #pragma unroll
  for (int it = 0; it < 2; ++it) {
    int c = it * 256 + tid;
    int d = c >> 3, tc = c & 7;
    u16 tmp[8];
    #pragma unroll
    for (int j = 0; j < 8; ++j)
      tmp[j] = vs[(size_t)(t0 + tc * 8 + j) * 64 + d];
    uint4 pk;
    pk.x = (u32)tmp[0] | ((u32)tmp[1] << 16);
    pk.y = (u32)tmp[2] | ((u32)tmp[3] << 16);
    pk.z = (u32)tmp[4] | ((u32)tmp[5] << 16);
    pk.w = (u32)tmp[6] | ((u32)tmp[7] << 16);
    *(uint4*)(vd + (size_t)d * 2048 + t0 + tc * 8) = pk;
  }
}

// ---------- flash attention, S^T orientation, paired q-tiles --------------
// R4 = R0 skeleton (paired uniform blocks, sequential A/B sub-steps) +
//  (1) in-register P exchange (R3-verified): Ps LDS round-trip removed.
//  (2) double-buffered K/V LDS: ONE barrier/step (write goes to buf[1-p]
//      while reads hit buf[p]; the single end-of-step barrier orders both).
//      Stage loads issue at step head, LDS write after compute (T14).
//  (3) grid (64,16): linear id = bh + pair*64 -> id%8 = bh%8: all 16
//      pair-blocks of a head on one XCD (8 heads x 512KB = 4MB = L2),
//      co-resident in kt-lockstep for temporal L2 sharing.

// one sub-step against buffer P for one q-tile
#define ATTN_SUB(P, QF0, QF1, O, MI, LI, DIAG)                                 \
  {                                                                            \
    f32x4 st[4];                                                               \
    _Pragma("unroll")                                                          \
    for (int nt = 0; nt < 4; ++nt) {                                           \
      short8 kf0 = *(const short8*)(&Ks[P][(nt * 16 + l16) * 72 + quad * 8]);  \
      short8 kf1 = *(const short8*)(&Ks[P][(nt * 16 + l16) * 72 + 32 + quad * 8]); \
      f32x4 z4 = {0.f, 0.f, 0.f, 0.f};                                         \
      z4 = __builtin_amdgcn_mfma_f32_16x16x32_bf16(kf0, QF0, z4, 0, 0, 0);     \
      st[nt] = __builtin_amdgcn_mfma_f32_16x16x32_bf16(kf1, QF1, z4, 0, 0, 0); \
    }                                                                          \
    if (DIAG) {                                                                \
      int q_loc = wave * 16 + l16;                                             \
      _Pragma("unroll")                                                        \
      for (int nt = 0; nt < 4; ++nt) {                                         \
        _Pragma("unroll")                                                      \
        for (int r = 0; r < 4; ++r) {                                          \
          int k_loc = nt * 16 + quad * 4 + r;                                  \
          if (k_loc > q_loc) st[nt][r] = -1e30f;                               \
        }                                                                      \
      }                                                                        \
    }                                                                          \
    float mq[4];                                                               \
    _Pragma("unroll")                                                          \
    for (int nt = 0; nt < 4; ++nt)                                             \
      mq[nt] = fmaxf(fmaxf(st[nt][0], st[nt][1]), fmaxf(st[nt][2], st[nt][3]));\
    float mx = fmaxf(fmaxf(mq[0], mq[1]), fmaxf(mq[2], mq[3]));                \
    mx = fmaxf(mx, __shfl_xor(mx, 16, 64));                                    \
    mx = fmaxf(mx, __shfl_xor(mx, 32, 64));                                    \
    float mnew = fmaxf(MI, mx);                                                \
    float alpha = EXP2(MI - mnew);                                             \
    MI = mnew;                                                                 \
    LI *= alpha;                                                               \
    _Pragma("unroll")                                                          \
    for (int r = 0; r < 4; ++r) {                                              \
      float av = __shfl(alpha, quad * 4 + r, 16);                              \
      _Pragma("unroll")                                                        \
      for (int dt = 0; dt < 4; ++dt) O[dt][r] *= av;                           \
    }                                                                          \
    u32 Wx[4], Wy[4];                                                          \
    float sq[4];                                                               \
    _Pragma("unroll")                                                          \
    for (int nt = 0; nt < 4; ++nt) {                                           \
      float p0 = EXP2(st[nt][0] - mnew);                                       \
      float p1 = EXP2(st[nt][1] - mnew);                                       \
      float p2 = EXP2(st[nt][2] - mnew);                                       \
      float p3 = EXP2(st[nt][3] - mnew);                                       \
      sq[nt] = (p0 + p1) + (p2 + p3);                                          \
      Wx[nt] = f2bf(p0) | (f2bf(p1) << 16);                                    \
      Wy[nt] = f2bf(p2) | (f2bf(p3) << 16);                                    \
    }                                                                          \
    float sum = (sq[0] + sq[1]) + (sq[2] + sq[3]);                             \
    sum += __shfl_xor(sum, 16, 64);                                            \
    sum += __shfl_xor(sum, 32, 64);                                            \
    LI += sum;                                                                 \
    uint4 t0, t1;                                                              \
    {                                                                          \
      u32 e, f;                                                                \
      e = __shfl(Wx[0], s0, 64); f = __shfl(Wx[1], s0, 64); t0.x = hi ? f : e; \
      e = __shfl(Wy[0], s0, 64); f = __shfl(Wy[1], s0, 64); t0.y = hi ? f : e; \
      e = __shfl(Wx[0], s1, 64); f = __shfl(Wx[1], s1, 64); t0.z = hi ? f : e; \
      e = __shfl(Wy[0], s1, 64); f = __shfl(Wy[1], s1, 64); t0.w = hi ? f : e; \
      e = __shfl(Wx[2], s0, 64); f = __shfl(Wx[3], s0, 64); t1.x = hi ? f : e; \
      e = __shfl(Wy[2], s0, 64); f = __shfl(Wy[3], s0, 64); t1.y = hi ? f : e; \
      e = __shfl(Wx[2], s1, 64); f = __shfl(Wx[3], s1, 64); t1.z = hi ? f : e; \
      e = __shfl(Wy[2], s1, 64); f = __shfl(Wy[3], s1, 64); t1.w = hi ? f : e; \
    }                                                                          \
    short8 pf0 = __builtin_bit_cast(short8, t0);                               \
    short8 pf1 = __builtin_bit_cast(short8, t1);                               \
    _Pragma("unroll")                                                          \
    for (int dt = 0; dt < 4; ++dt) {                                           \
      short8 vf0 = *(const short8*)(&Vs[P][(dt * 16 + l16) * 72 + quad * 8]);  \
      short8 vf1 = *(const short8*)(&Vs[P][(dt * 16 + l16) * 72 + 32 + quad * 8]); \
      O[dt] = __builtin_amdgcn_mfma_f32_16x16x32_bf16(pf0, vf0, O[dt], 0, 0, 0); \
      O[dt] = __builtin_amdgcn_mfma_f32_16x16x32_bf16(pf1, vf1, O[dt], 0, 0, 0); \
    }                                                                          \
  }

#define ATTN_EPI(O, LI, QT)                                                    \
  _Pragma("unroll")                                                            \
  for (int r = 0; r < 4; ++r) {                                                \
    float lv = __shfl(LI, quad * 4 + r, 16);                                   \
    float inv = 1.0f / lv;                                                     \
    int t = (QT) * 64 + wave * 16 + quad * 4 + r;                              \
    _Pragma("unroll")                                                          \
    for (int dt = 0; dt < 4; ++dt) {                                           \
      int d = dt * 16 + l16;                                                   \
      y[(((size_t)b * 2048 + t) * NH + h) * 64 + d] = (u16)f2bf(O[dt][r] * inv); \
    }                                                                          \
  }

__global__ __launch_bounds__(256, 4) void k_attn(
    const u16* __restrict__ q, const u16* __restrict__ k,
    const u16* __restrict__ vt, u16* __restrict__ y) {
  const int tid = threadIdx.x;
  const int wave = tid >> 6, lane = tid & 63;
  const int quad = lane >> 4, l16 = lane & 15;
  const int bh = blockIdx.x, bx = blockIdx.y;  // grid (64,16): id%8 = bh%8
  const int qtB = bx, qtA = 31 - bx;           // qtB in 0..15, qtA in 16..31
  const int b = bh >> 4, h = bh & 15;

  __shared__ u16 Ks[2][64 * 72];
  __shared__ u16 Vs[2][64 * 72];               // [d][kidx]

  const u16* qbA = q + ((size_t)bh * 2048 + qtA * 64 + wave * 16 + l16) * 64;
  short8 qA0 = *(const short8*)(qbA + quad * 8);
  short8 qA1 = *(const short8*)(qbA + 32 + quad * 8);
  const u16* qbB = q + ((size_t)bh * 2048 + qtB * 64 + wave * 16 + l16) * 64;
  short8 qB0 = *(const short8*)(qbB + quad * 8);
  short8 qB1 = *(const short8*)(qbB + 32 + quad * 8);

  f32x4 oA[4], oB[4];
  {
    f32x4 z = {0.f, 0.f, 0.f, 0.f};
    #pragma unroll
    for (int dt = 0; dt < 4; ++dt) { oA[dt] = z; oB[dt] = z; }
  }
  float mA = -1e30f, lA = 0.f, mB = -1e30f, lB = 0.f;

  const u16* kbase = k + (size_t)bh * 131072;
  const u16* vbase = vt + (size_t)bh * 131072;
  const int r0 = tid >> 3, cc = tid & 7;
  // P-exchange source lanes: receiver (quad,ks) pulls W[2ks+hi] words from
  // lanes s0 (j=0..3) and s1 (j=4..7)  [verified R3]
  const int s0 = ((quad & 1) << 5) + l16, s1 = s0 + 16;
  const int hi = quad >> 1;

  // prologue: stage kt=0 into buffer 0
  {
    uint4 k0 = *(const uint4*)(kbase + (size_t)r0 * 64 + cc * 8);
    uint4 k1 = *(const uint4*)(kbase + (size_t)(r0 + 32) * 64 + cc * 8);
    uint4 v0 = *(const uint4*)(vbase + (size_t)r0 * 2048 + cc * 8);
    uint4 v1 = *(const uint4*)(vbase + (size_t)(r0 + 32) * 2048 + cc * 8);
    *(uint4*)(&Ks[0][r0 * 72 + cc * 8]) = k0;
    *(uint4*)(&Ks[0][(r0 + 32) * 72 + cc * 8]) = k1;
    *(uint4*)(&Vs[0][r0 * 72 + cc * 8]) = v0;
    *(uint4*)(&Vs[0][(r0 + 32) * 72 + cc * 8]) = v1;
  }
  __syncthreads();

  for (int kt = 0; kt <= qtA; ++kt) {
    const int p = kt & 1;
    const bool pre = (kt < qtA);
    uint4 kr0, kr1, vr0, vr1;
    if (pre) {  // issue next-tile loads early; consumed after compute
      const u16* kb = kbase + (size_t)(kt + 1) * 4096;
      const u16* vb = vbase + (kt + 1) * 64;
      kr0 = *(const uint4*)(kb + (size_t)r0 * 64 + cc * 8);
      kr1 = *(const uint4*)(kb + (size_t)(r0 + 32) * 64 + cc * 8);
      vr0 = *(const uint4*)(vb + (size_t)r0 * 2048 + cc * 8);
      vr1 = *(const uint4*)(vb + (size_t)(r0 + 32) * 2048 + cc * 8);
    }

    ATTN_SUB(p, qA0, qA1, oA, mA, lA, (kt == qtA))
    if (kt <= qtB) {
      ATTN_SUB(p, qB0, qB1, oB, mB, lB, (kt == qtB))
    }

    if (pre) {  // write next tile into the other buffer
      *(uint4*)(&Ks[p ^ 1][r0 * 72 + cc * 8]) = kr0;
      *(uint4*)(&Ks[p ^ 1][(r0 + 32) * 72 + cc * 8]) = kr1;
      *(uint4*)(&Vs[p ^ 1][r0 * 72 + cc * 8]) = vr0;
      *(uint4*)(&Vs[p ^ 1][(r0 + 32) * 72 + cc * 8]) = vr1;
    }
    __syncthreads();  // single barrier: orders buf[p^1] writes + buf[p] reads
  }

  ATTN_EPI(oA, lA, qtA)
  ATTN_EPI(oB, lB, qtB)
}

extern "C" void kernel_launch(void* const* d_in, const int* in_sizes, int n_in,
                              void* d_out, int out_size, void* d_ws, size_t ws_size,
                              hipStream_t stream) {
  const float* x  = (const float*)d_in[0];
  const float* Wq = (const float*)d_in[1];
  const float* bq = (const float*)d_in[2];
  const float* Wk = (const float*)d_in[3];
  const float* bk = (const float*)d_in[4];
  const float* Wv = (const float*)d_in[5];
  const float* bv = (const float*)d_in[6];
  const float* Wo = (const float*)d_in[7];
  const float* bo = (const float*)d_in[8];
  float* out = (float*)d_out;

  u16* ws  = (u16*)d_ws;
  u16* xb  = ws;                   // 8388608   x bf16 [8192][1024]
  u16* Wb  = ws + 8388608;         // 4x1048576 Wq|Wk|Wv|Wo bf16
  u16* qkv = ws + 12582912;        // 3x8388608 q|k|v [B,H,T,Dh] bf16
  u16* vt  = ws + 37748736;        // 8388608   v^T [B,H,Dh,T] bf16
  u16* y   = ws + 46137344;        // 8388608   attn out [B,T,H,Dh] bf16

  k_convert<<<dim3(12288), dim3(256), 0, stream>>>(x, Wq, Wk, Wv, Wo, ws);
  k_gemm_qkv<<<dim3(8, 64, 3), dim3(256), 0, stream>>>(xb, Wb, bq, bk, bv, qkv);
  k_vtrans<<<dim3(32, 64), dim3(256), 0, stream>>>(qkv + 2 * 8388608, vt);
  k_attn<<<dim3(64, 16), dim3(256), 0, stream>>>(qkv, qkv + 8388608, vt, y);
  k_gemm_out<<<dim3(8, 64), dim3(256), 0, stream>>>(y, Wb + 3 * 1048576, bo, out);
}